// Round 12
// baseline (819.128 us; speedup 1.0000x reference)
//
#include <hip/hip_runtime.h>
#include <cstdint>
#include <cstddef>

// Problem constants (fixed by the reference setup_inputs).
#define NN 100000
#define EE 500000
#define DD 128
#define GG 512
#define LL 4
#define BN_EPS 1e-5f

typedef __attribute__((ext_vector_type(8))) short short8;
typedef __attribute__((ext_vector_type(8))) unsigned short ushort8v;
typedef __attribute__((ext_vector_type(4))) float f32x4;

static __device__ __forceinline__ unsigned short f2bf(float f) {
  union { float f; unsigned u; } v;
  v.f = f;
  unsigned r = v.u + 0x7fffu + ((v.u >> 16) & 1u);  // RNE
  return (unsigned short)(r >> 16);
}
static __device__ __forceinline__ float bf2f(unsigned short u) {
  union { unsigned u; float f; } v;
  v.u = ((unsigned)u) << 16;
  return v.f;
}

// ---------------- CSR build (int32 inputs) ----------------

__global__ void k_hist(const int* __restrict__ ei, int* __restrict__ cnt) {
  int e = blockIdx.x * 256 + threadIdx.x;
  if (e < EE) {
    int d = ei[EE + e];
    if (d >= 0 && d < NN) atomicAdd(&cnt[d], 1);
  }
}

__global__ void k_part(const int* __restrict__ cnt, int* __restrict__ part) {
  __shared__ int sm[1024];
  int t = threadIdx.x;
  int i = blockIdx.x * 1024 + t;
  sm[t] = (i < NN) ? cnt[i] : 0;
  __syncthreads();
  for (int off = 512; off > 0; off >>= 1) {
    if (t < off) sm[t] += sm[t + off];
    __syncthreads();
  }
  if (t == 0) part[blockIdx.x] = sm[0];
}

__global__ void k_scanpart(const int* __restrict__ part, int* __restrict__ partx, int nb) {
  __shared__ int sm[128];
  int t = threadIdx.x;
  int v = (t < nb) ? part[t] : 0;
  sm[t] = v;
  __syncthreads();
  for (int off = 1; off < 128; off <<= 1) {
    int u = (t >= off) ? sm[t - off] : 0;
    __syncthreads();
    sm[t] += u;
    __syncthreads();
  }
  if (t < nb) partx[t] = sm[t] - v;
}

__global__ void k_rs(const int* __restrict__ cnt, const int* __restrict__ partx,
                     int* __restrict__ rs, int* __restrict__ cur) {
  __shared__ int sm[1024];
  int t = threadIdx.x;
  int i = blockIdx.x * 1024 + t;
  int v = (i < NN) ? cnt[i] : 0;
  sm[t] = v;
  __syncthreads();
  for (int off = 1; off < 1024; off <<= 1) {
    int u = (t >= off) ? sm[t - off] : 0;
    __syncthreads();
    sm[t] += u;
    __syncthreads();
  }
  if (i < NN) {
    int excl = partx[blockIdx.x] + sm[t] - v;
    rs[i] = excl;
    cur[i] = excl;
    if (i == NN - 1) rs[NN] = excl + v;
  }
}

__global__ void k_fill(const int* __restrict__ ei, int* __restrict__ cur,
                       int* __restrict__ ci) {
  int e = blockIdx.x * 256 + threadIdx.x;
  if (e < EE) {
    int s = ei[e];
    int d = ei[EE + e];
    if (d >= 0 && d < NN && s >= 0 && s < NN) {
      int pos = atomicAdd(&cur[d], 1);
      if (pos >= 0 && pos < EE) ci[pos] = s;  // order irrelevant (sum)
    }
  }
}

// ---------------- weight convert: W -> W^T in bf16, once per call ----------------

__global__ void k_conv(const float* __restrict__ W1, const float* __restrict__ W2,
                       unsigned short* __restrict__ W1t, unsigned short* __restrict__ W2t) {
  int idx = blockIdx.x * 256 + threadIdx.x;
  if (idx < 4 * 256 * 128) {
    {  // W1: [l][k][nc] (K=128,NC=256) -> [l][nc][k]
      int l = idx >> 15, rem = idx & 32767;
      int nc = rem >> 7, k = rem & 127;
      W1t[idx] = f2bf(W1[(l << 15) + k * 256 + nc]);
    }
    {  // W2: [l][k][nc] (K=256,NC=128) -> [l][nc][k]
      int l = idx >> 15, rem = idx & 32767;
      int nc = rem >> 8, k = rem & 255;
      W2t[idx] = f2bf(W2[(l << 15) + k * 128 + nc]);
    }
  }
}

// ---------------- x -> bf16 convert (streaming, once per call) ----------------

__global__ void k_x2bf(const float* __restrict__ x, unsigned short* __restrict__ xb) {
  int i = blockIdx.x * 256 + threadIdx.x;
  if (i < NN * DD / 4) {
    float4 v = *(const float4*)(x + (size_t)i * 4);
    ushort4 o;
    o.x = f2bf(v.x); o.y = f2bf(v.y); o.z = f2bf(v.z); o.w = f2bf(v.w);
    *(ushort4*)(xb + (size_t)i * 4) = o;
  }
}

// ---------------- aggregation: bf16 X in (opt. BN/ReLU), bf16 h0 out ----

__global__ __launch_bounds__(256) void k_agg_bf16(
    const unsigned short* __restrict__ X, const int* __restrict__ rs,
    const int* __restrict__ ci, const float* __restrict__ epsv, int l, int mode,
    const float* __restrict__ tsc, const float* __restrict__ tsh,
    unsigned short* __restrict__ h0, int n) {
  int idx = blockIdx.x * 256 + threadIdx.x;
  int node = idx >> 4;
  int c8 = (idx & 15) << 3;
  if (node >= n) return;
  float sa[8], sb[8];
  if (mode) {
    float4 a0 = *(const float4*)(tsc + c8), a1 = *(const float4*)(tsc + c8 + 4);
    float4 b0 = *(const float4*)(tsh + c8), b1 = *(const float4*)(tsh + c8 + 4);
    sa[0] = a0.x; sa[1] = a0.y; sa[2] = a0.z; sa[3] = a0.w;
    sa[4] = a1.x; sa[5] = a1.y; sa[6] = a1.z; sa[7] = a1.w;
    sb[0] = b0.x; sb[1] = b0.y; sb[2] = b0.z; sb[3] = b0.w;
    sb[4] = b1.x; sb[5] = b1.y; sb[6] = b1.z; sb[7] = b1.w;
  }
  float se = 1.f + epsv[l];
  ushort8v v = *(const ushort8v*)(X + (size_t)node * DD + c8);
  float acc[8];
#pragma unroll
  for (int j = 0; j < 8; ++j) {
    float f = bf2f(v[j]);
    if (mode) f = fmaxf(0.f, f * sa[j] + sb[j]);
    acc[j] = se * f;
  }
  int e0 = rs[node], e1 = rs[node + 1];
  ushort8v un;
  if (e0 < e1) un = *(const ushort8v*)(X + (size_t)ci[e0] * DD + c8);
  for (int e = e0; e < e1; ++e) {
    ushort8v uc = un;
    if (e + 1 < e1) un = *(const ushort8v*)(X + (size_t)ci[e + 1] * DD + c8);
#pragma unroll
    for (int j = 0; j < 8; ++j) {
      float f = bf2f(uc[j]);
      if (mode) f = fmaxf(0.f, f * sa[j] + sb[j]);
      acc[j] += f;
    }
  }
  ushort8v o;
#pragma unroll
  for (int j = 0; j < 8; ++j) o[j] = f2bf(acc[j]);
  *(ushort8v*)(h0 + (size_t)node * DD + c8) = o;
}

// ---------------- GEMM1 stats-only: column (sum,sumsq) of h0@W1+b1 ----------------
// GM=128 rows, 512 threads = 8 waves x 16 rows. Full-K A panel staged once
// (single HBM-latency phase); W1 tiles are L2-hot. NO C write.

__global__ __launch_bounds__(512) void k_gstat(
    const unsigned short* __restrict__ A, const unsigned short* __restrict__ Bt,
    const float* __restrict__ bias, float* __restrict__ psum,
    float* __restrict__ psq, int n) {
  constexpr int AST = 136;  // 272B row stride
  __shared__ __align__(16) unsigned short As[128 * AST];
  __shared__ __align__(16) unsigned short Bs[128 * AST];
  __shared__ float bsum[128], bsq[128];
  int tid = threadIdx.x;
  int lane = tid & 63, wave = tid >> 6;
  int quad = lane >> 4, l15 = lane & 15;
  int row0 = blockIdx.x * 128;
  int blk = blockIdx.x;

  // stage A full-K: 128 rows x 128 k (2048 ushort8, 4/thread)
#pragma unroll
  for (int it = 0; it < 4; ++it) {
    int f = tid + it * 512;
    int r = f >> 4;
    int c8 = (f & 15) << 3;
    int gr = row0 + r;
    ushort8v v = (ushort8v){0, 0, 0, 0, 0, 0, 0, 0};
    if (gr < n) v = *(const ushort8v*)(A + (size_t)gr * 128 + c8);
    *(ushort8v*)(&As[r * AST + c8]) = v;
  }

  for (int cg = 0; cg < 2; ++cg) {
    // stage W1 cols cg*128.. : [128][128]
#pragma unroll
    for (int it = 0; it < 4; ++it) {
      int f = tid + it * 512;
      int r = f >> 4;
      int c8 = (f & 15) << 3;
      *(ushort8v*)(&Bs[r * AST + c8]) =
          *(const ushort8v*)(Bt + (size_t)(cg * 128 + r) * 128 + c8);
    }
    if (tid < 128) { bsum[tid] = 0.f; bsq[tid] = 0.f; }
    __syncthreads();  // As+Bs+bsum ready

    f32x4 acc[8];
#pragma unroll
    for (int j = 0; j < 8; ++j) acc[j] = (f32x4){0.f, 0.f, 0.f, 0.f};
#pragma unroll
    for (int kk = 0; kk < 128; kk += 32) {
      int ko = kk + quad * 8;
      short8 av = *(const short8*)(&As[(wave * 16 + l15) * AST + ko]);
#pragma unroll
      for (int cf = 0; cf < 8; ++cf) {
        short8 bv = *(const short8*)(&Bs[(cf * 16 + l15) * AST + ko]);
        acc[cf] = __builtin_amdgcn_mfma_f32_16x16x32_bf16(av, bv, acc[cf], 0, 0, 0);
      }
    }
    // stats: C/D layout col=l15, row=quad*4+reg
    float s8[8], q8[8];
#pragma unroll
    for (int j = 0; j < 8; ++j) { s8[j] = 0.f; q8[j] = 0.f; }
    int lrbase = wave * 16 + quad * 4;
#pragma unroll
    for (int cf = 0; cf < 8; ++cf) {
      float bv = bias[cg * 128 + cf * 16 + l15];
#pragma unroll
      for (int reg = 0; reg < 4; ++reg) {
        if (row0 + lrbase + reg < n) {
          float e = acc[cf][reg] + bv;
          s8[cf] += e;
          q8[cf] += e * e;
        }
      }
    }
#pragma unroll
    for (int cf = 0; cf < 8; ++cf) {
      s8[cf] += __shfl_xor(s8[cf], 16, 64);
      s8[cf] += __shfl_xor(s8[cf], 32, 64);
      q8[cf] += __shfl_xor(q8[cf], 16, 64);
      q8[cf] += __shfl_xor(q8[cf], 32, 64);
    }
    if (quad == 0) {
#pragma unroll
      for (int cf = 0; cf < 8; ++cf) {
        atomicAdd(&bsum[cf * 16 + l15], s8[cf]);
        atomicAdd(&bsq[cf * 16 + l15], q8[cf]);
      }
    }
    __syncthreads();  // atomics done; also protects Bs for next cg
    if (tid < 128) {
      psum[(size_t)blk * 256 + cg * 128 + tid] = bsum[tid];
      psq[(size_t)blk * 256 + cg * 128 + tid] = bsq[tid];
    }
  }
}

// ---------------- fused: xp = bn2(relu(bn1(h0@W1+b1))@W2+b2)-input + stats -------
// h1 recomputed tile-locally (bit-identical to k_gstat's values), BN1+ReLU via
// tsc1/tsh1 into LDS Ht (C-layout -> LDS -> A-layout round-trip), then GEMM2
// from LDS against W2. Writes xp (bf16) + column partials. LDS ~135KB, 1 blk/CU.

__global__ __launch_bounds__(512) void k_fused(
    const unsigned short* __restrict__ A, const unsigned short* __restrict__ B1t,
    const float* __restrict__ b1, const float* __restrict__ tsc1,
    const float* __restrict__ tsh1, const unsigned short* __restrict__ B2t,
    const float* __restrict__ b2, unsigned short* __restrict__ C,
    float* __restrict__ psum, float* __restrict__ psq, int n) {
  constexpr int AST = 136;  // A/W stage row stride (ushorts)
  constexpr int HST = 264;  // Ht row stride (ushorts), 528B
  __shared__ __align__(16) unsigned short As[128 * AST];  // 34816 B (reused as Ct)
  __shared__ __align__(16) unsigned short Ws[128 * AST];  // 34816 B
  __shared__ __align__(16) unsigned short Ht[128 * HST];  // 67584 B
  __shared__ float bsum[128], bsq[128];
  int tid = threadIdx.x;
  int lane = tid & 63, wave = tid >> 6;
  int quad = lane >> 4, l15 = lane & 15;
  int row0 = blockIdx.x * 128;
  int blk = blockIdx.x;

  // stage A (h0) full-K: 128x128
#pragma unroll
  for (int it = 0; it < 4; ++it) {
    int f = tid + it * 512;
    int r = f >> 4;
    int c8 = (f & 15) << 3;
    int gr = row0 + r;
    ushort8v v = (ushort8v){0, 0, 0, 0, 0, 0, 0, 0};
    if (gr < n) v = *(const ushort8v*)(A + (size_t)gr * 128 + c8);
    *(ushort8v*)(&As[r * AST + c8]) = v;
  }

  // ---- GEMM1 recompute + BN1 + ReLU -> Ht ----
  for (int cg = 0; cg < 2; ++cg) {
#pragma unroll
    for (int it = 0; it < 4; ++it) {
      int f = tid + it * 512;
      int r = f >> 4;
      int c8 = (f & 15) << 3;
      *(ushort8v*)(&Ws[r * AST + c8]) =
          *(const ushort8v*)(B1t + (size_t)(cg * 128 + r) * 128 + c8);
    }
    if (cg == 0 && tid < 128) { bsum[tid] = 0.f; bsq[tid] = 0.f; }
    __syncthreads();  // As+Ws ready

    f32x4 acc[8];
#pragma unroll
    for (int j = 0; j < 8; ++j) acc[j] = (f32x4){0.f, 0.f, 0.f, 0.f};
#pragma unroll
    for (int kk = 0; kk < 128; kk += 32) {
      int ko = kk + quad * 8;
      short8 av = *(const short8*)(&As[(wave * 16 + l15) * AST + ko]);
#pragma unroll
      for (int cf = 0; cf < 8; ++cf) {
        short8 bv = *(const short8*)(&Ws[(cf * 16 + l15) * AST + ko]);
        acc[cf] = __builtin_amdgcn_mfma_f32_16x16x32_bf16(av, bv, acc[cf], 0, 0, 0);
      }
    }
    // BN1+ReLU -> Ht (scattered ushort LDS writes; C-layout)
    int lrbase = wave * 16 + quad * 4;
#pragma unroll
    for (int cf = 0; cf < 8; ++cf) {
      int col = cg * 128 + cf * 16 + l15;
      float bv = b1[col];
      float sc = tsc1[col], sh = tsh1[col];
#pragma unroll
      for (int reg = 0; reg < 4; ++reg) {
        float e = acc[cf][reg] + bv;
        float hn = fmaxf(0.f, e * sc + sh);
        Ht[(lrbase + reg) * HST + col] = f2bf(hn);
      }
    }
    __syncthreads();  // Ht writes drained; Ws reusable
  }

  // ---- GEMM2: Ht (LDS) @ W2 -> xp ----
  f32x4 acc2[8];
#pragma unroll
  for (int j = 0; j < 8; ++j) acc2[j] = (f32x4){0.f, 0.f, 0.f, 0.f};
  for (int kc = 0; kc < 2; ++kc) {
#pragma unroll
    for (int it = 0; it < 4; ++it) {
      int f = tid + it * 512;
      int r = f >> 4;
      int c8 = (f & 15) << 3;
      *(ushort8v*)(&Ws[r * AST + c8]) =
          *(const ushort8v*)(B2t + (size_t)r * 256 + kc * 128 + c8);
    }
    __syncthreads();  // Ws ready (and prior-phase reads done)
#pragma unroll
    for (int kk = 0; kk < 128; kk += 32) {
      int ko = kk + quad * 8;
      short8 av = *(const short8*)(&Ht[(wave * 16 + l15) * HST + kc * 128 + ko]);
#pragma unroll
      for (int cf = 0; cf < 8; ++cf) {
        short8 bv = *(const short8*)(&Ws[(cf * 16 + l15) * AST + ko]);
        acc2[cf] = __builtin_amdgcn_mfma_f32_16x16x32_bf16(av, bv, acc2[cf], 0, 0, 0);
      }
    }
    __syncthreads();  // Ws reads done before next stage / epilogue As reuse
  }

  // ---- epilogue: bias2, Ct (reuse As), stats, coalesced store ----
  unsigned short* Ct = As;
  float s8[8], q8[8];
#pragma unroll
  for (int j = 0; j < 8; ++j) { s8[j] = 0.f; q8[j] = 0.f; }
  int lrbase = wave * 16 + quad * 4;
#pragma unroll
  for (int cf = 0; cf < 8; ++cf) {
    int col = cf * 16 + l15;
    float bv = b2[col];
#pragma unroll
    for (int reg = 0; reg < 4; ++reg) {
      int lr = lrbase + reg;
      float e = acc2[cf][reg] + bv;
      Ct[lr * AST + col] = f2bf(e);
      if (row0 + lr < n) { s8[cf] += e; q8[cf] += e * e; }
    }
  }
#pragma unroll
  for (int cf = 0; cf < 8; ++cf) {
    s8[cf] += __shfl_xor(s8[cf], 16, 64);
    s8[cf] += __shfl_xor(s8[cf], 32, 64);
    q8[cf] += __shfl_xor(q8[cf], 16, 64);
    q8[cf] += __shfl_xor(q8[cf], 32, 64);
  }
  if (quad == 0) {
#pragma unroll
    for (int cf = 0; cf < 8; ++cf) {
      atomicAdd(&bsum[cf * 16 + l15], s8[cf]);
      atomicAdd(&bsq[cf * 16 + l15], q8[cf]);
    }
  }
  __syncthreads();  // Ct + bsum complete
  // coalesced xp store: 128 rows x 128 cols = 2048 ushort8, 4/thread
#pragma unroll
  for (int it = 0; it < 4; ++it) {
    int f = tid + it * 512;
    int r = f >> 4;
    int c8 = (f & 15) << 3;
    int gr = row0 + r;
    if (gr < n)
      *(ushort8v*)(C + (size_t)gr * 128 + c8) = *(const ushort8v*)(&Ct[r * AST + c8]);
  }
  if (tid < 128) {
    psum[(size_t)blk * 128 + tid] = bsum[tid];
    psq[(size_t)blk * 128 + tid] = bsq[tid];
  }
}

// ---------------- column-stat reduce + BN finalize (one block per column) --------

__global__ __launch_bounds__(256) void k_finred(
    const float* __restrict__ psum, const float* __restrict__ psq, int nb, int nc,
    const float* __restrict__ g, const float* __restrict__ be,
    float* __restrict__ osc, float* __restrict__ osh, float invn) {
  __shared__ float ws[4], wq[4];
  int col = blockIdx.x;
  int t = threadIdx.x;
  float s = 0.f, q = 0.f;
  for (int b = t; b < nb; b += 256) {
    s += psum[(size_t)b * nc + col];
    q += psq[(size_t)b * nc + col];
  }
#pragma unroll
  for (int off = 32; off > 0; off >>= 1) {
    s += __shfl_xor(s, off, 64);
    q += __shfl_xor(q, off, 64);
  }
  if ((t & 63) == 0) { ws[t >> 6] = s; wq[t >> 6] = q; }
  __syncthreads();
  if (t == 0) {
    s = ws[0] + ws[1] + ws[2] + ws[3];
    q = wq[0] + wq[1] + wq[2] + wq[3];
    float m = s * invn;
    float v = fmaxf(q * invn - m * m, 0.f);
    float sc = g[col] * rsqrtf(v + BN_EPS);
    osc[col] = sc;
    osh[col] = be[col] - m * sc;
  }
}

// ---------------- classifier z1 stats ----------------

__global__ __launch_bounds__(256) void k_statz(
    const float* __restrict__ z1, const float* __restrict__ g,
    const float* __restrict__ be, float* __restrict__ osc, float* __restrict__ osh) {
  __shared__ float ws[4], wq[4];
  int col = blockIdx.x;
  int t = threadIdx.x;
  float s = 0.f, q = 0.f;
  for (int b = t; b < GG; b += 256) {
    float v = z1[(size_t)b * 128 + col];
    s += v;
    q += v * v;
  }
#pragma unroll
  for (int off = 32; off > 0; off >>= 1) {
    s += __shfl_xor(s, off, 64);
    q += __shfl_xor(q, off, 64);
  }
  if ((t & 63) == 0) { ws[t >> 6] = s; wq[t >> 6] = q; }
  __syncthreads();
  if (t == 0) {
    s = ws[0] + ws[1] + ws[2] + ws[3];
    q = wq[0] + wq[1] + wq[2] + wq[3];
    float m = s / (float)GG;
    float v = fmaxf(q / (float)GG - m * m, 0.f);
    float sc = g[col] * rsqrtf(v + BN_EPS);
    osc[col] = sc;
    osh[col] = be[col] - m * sc;
  }
}

// ---------------- pooling (batch sorted -> contiguous ranges), bf16 X ------------

static __device__ __forceinline__ int lb_i32(const int* a, int n, int key) {
  int lo = 0, hi = n;
  while (lo < hi) {
    int mid = (lo + hi) >> 1;
    if (a[mid] < key) lo = mid + 1; else hi = mid;
  }
  return lo;
}

__global__ __launch_bounds__(512) void k_pool(
    const unsigned short* __restrict__ X, const int* __restrict__ batch,
    const float* __restrict__ tsc, const float* __restrict__ tsh,
    float* __restrict__ z, int n) {
  __shared__ int slo, shi;
  __shared__ float ssum[8][128], smax[8][128];
  int g = blockIdx.x;
  int t = threadIdx.x;
  int sg = t >> 6;
  int c2 = (t & 63) << 1;
  if (t == 0) {
    slo = lb_i32(batch, n, g);
    shi = lb_i32(batch, n, g + 1);
  }
  __syncthreads();
  int lo = slo, hi = shi;
  float a0 = tsc[c2], a1 = tsc[c2 + 1];
  float b0 = tsh[c2], b1 = tsh[c2 + 1];
  float s0 = 0.f, s1 = 0.f;
  float m0 = -3.402823466e38f, m1 = -3.402823466e38f;
  for (int i = lo + sg; i < hi; i += 8) {
    unsigned u = *(const unsigned*)(X + (size_t)i * DD + c2);
    float v0 = fmaxf(0.f, bf2f((unsigned short)(u & 0xffff)) * a0 + b0);
    float v1 = fmaxf(0.f, bf2f((unsigned short)(u >> 16)) * a1 + b1);
    s0 += v0; m0 = fmaxf(m0, v0);
    s1 += v1; m1 = fmaxf(m1, v1);
  }
  ssum[sg][c2] = s0; ssum[sg][c2 + 1] = s1;
  smax[sg][c2] = m0; smax[sg][c2 + 1] = m1;
  __syncthreads();
  if (t < 128) {
    float S = 0.f, M = -3.402823466e38f;
#pragma unroll
    for (int k = 0; k < 8; ++k) {
      S += ssum[k][t];
      M = fmaxf(M, smax[k][t]);
    }
    float cntf = (float)(hi - lo);
    z[(size_t)g * 384 + t] = S;
    z[(size_t)g * 384 + 128 + t] = S / fmaxf(cntf, 1.f);
    z[(size_t)g * 384 + 256 + t] = M;
  }
}

// ---------------- classifier head (fp32, tiny; no atomics) ----------------

__global__ void k_cls1(const float* __restrict__ z, const float* __restrict__ cW1,
                       const float* __restrict__ cb1, float* __restrict__ z1) {
  __shared__ float zr[384];
  int g = blockIdx.x;
  int c = threadIdx.x;  // 128
  for (int i = c; i < 384; i += 128) zr[i] = z[(size_t)g * 384 + i];
  __syncthreads();
  float s = cb1[c];
#pragma unroll 4
  for (int k = 0; k < 384; ++k) s = fmaf(zr[k], cW1[(size_t)k * 128 + c], s);
  z1[(size_t)g * 128 + c] = s;
}

__global__ void k_cls2(const float* __restrict__ z1, const float* __restrict__ csc,
                       const float* __restrict__ csh, const float* __restrict__ cW2,
                       const float* __restrict__ cb2, const float* __restrict__ cW3,
                       const float* __restrict__ cb3, float* __restrict__ out) {
  __shared__ float z1n[128];
  __shared__ float z2s[64];
  int g = blockIdx.x;
  int t = threadIdx.x;  // 128
  z1n[t] = fmaxf(0.f, z1[(size_t)g * 128 + t] * csc[t] + csh[t]);
  __syncthreads();
  if (t < 64) {
    float s = cb2[t];
#pragma unroll 4
    for (int k = 0; k < 128; ++k) s = fmaf(z1n[k], cW2[(size_t)k * 64 + t], s);
    z2s[t] = fmaxf(0.f, s);
  }
  __syncthreads();
  if (t < 2) {
    float s = cb3[t];
#pragma unroll 4
    for (int c = 0; c < 64; ++c) s = fmaf(z2s[c], cW3[(size_t)c * 2 + t], s);
    out[(size_t)g * 2 + t] = s;
  }
}

// ---------------- launch ----------------

extern "C" void kernel_launch(void* const* d_in, const int* in_sizes, int n_in,
                              void* d_out, int out_size, void* d_ws, size_t ws_size,
                              hipStream_t stream) {
  const float* x = (const float*)d_in[0];
  const int* ei = (const int*)d_in[1];     // int32 (harness downcasts int64)
  const int* batch = (const int*)d_in[2];  // int32
  const float* W1 = (const float*)d_in[4];
  const float* b1 = (const float*)d_in[5];
  const float* g1 = (const float*)d_in[6];
  const float* be1 = (const float*)d_in[7];
  const float* W2 = (const float*)d_in[8];
  const float* b2 = (const float*)d_in[9];
  const float* gbn = (const float*)d_in[10];
  const float* bbn = (const float*)d_in[11];
  const float* epsv = (const float*)d_in[12];
  const float* cW1 = (const float*)d_in[13];
  const float* cb1 = (const float*)d_in[14];
  const float* cg = (const float*)d_in[15];
  const float* cbeta = (const float*)d_in[16];
  const float* cW2 = (const float*)d_in[17];
  const float* cb2 = (const float*)d_in[18];
  const float* cW3 = (const float*)d_in[19];
  const float* cb3 = (const float*)d_in[20];
  float* out = (float*)d_out;

  char* p = (char*)d_ws;
  auto alloc = [&](size_t bytes) {
    char* r = p;
    p += (bytes + 255) & ~(size_t)255;
    return r;
  };
  const int NB = (NN + 127) / 128;  // 782 GEMM row-blocks
  int* cnt = (int*)alloc((size_t)NN * 4);
  int* rs = (int*)alloc((size_t)(NN + 1) * 4);
  int* cur = (int*)alloc((size_t)NN * 4);
  int* ci = (int*)alloc((size_t)EE * 4);
  int* part = (int*)alloc(128 * 4);
  int* partx = (int*)alloc(128 * 4);
  unsigned short* xbf = (unsigned short*)alloc((size_t)NN * DD * 2);
  unsigned short* h0 = (unsigned short*)alloc((size_t)NN * DD * 2);
  unsigned short* xp = (unsigned short*)alloc((size_t)NN * DD * 2);
  float* psum = (float*)alloc((size_t)NB * 256 * 4);
  float* psq = (float*)alloc((size_t)NB * 256 * 4);
  float* tsc1 = (float*)alloc(256 * 4);
  float* tsh1 = (float*)alloc(256 * 4);
  float* tscX = (float*)alloc(128 * 4);
  float* tshX = (float*)alloc(128 * 4);
  float* zbuf = (float*)alloc((size_t)GG * 384 * 4);
  float* z1 = (float*)alloc((size_t)GG * 128 * 4);
  unsigned short* W1t = (unsigned short*)alloc((size_t)4 * 256 * 128 * 2);
  unsigned short* W2t = (unsigned short*)alloc((size_t)4 * 128 * 256 * 2);
  (void)ws_size; (void)n_in; (void)in_sizes; (void)out_size;

  // weight convert+transpose to bf16 (static across layers/calls)
  k_conv<<<512, 256, 0, stream>>>(W1, W2, W1t, W2t);
  // x -> bf16
  k_x2bf<<<(NN * DD / 4 + 255) / 256, 256, 0, stream>>>(x, xbf);

  // CSR build (edges static across layers)
  hipMemsetAsync(cnt, 0, (size_t)NN * 4, stream);
  k_hist<<<(EE + 255) / 256, 256, 0, stream>>>(ei, cnt);
  const int nscan = (NN + 1023) / 1024;  // 98
  k_part<<<nscan, 1024, 0, stream>>>(cnt, part);
  k_scanpart<<<1, 128, 0, stream>>>(part, partx, nscan);
  k_rs<<<nscan, 1024, 0, stream>>>(cnt, partx, rs, cur);
  k_fill<<<(EE + 255) / 256, 256, 0, stream>>>(ei, cur, ci);

  for (int l = 0; l < LL; ++l) {
    const unsigned short* Xl = (l == 0) ? xbf : xp;
    k_agg_bf16<<<(NN * 16 + 255) / 256, 256, 0, stream>>>(
        Xl, rs, ci, epsv, l, (l > 0) ? 1 : 0, tscX, tshX, h0, NN);
    k_gstat<<<NB, 512, 0, stream>>>(h0, W1t + (size_t)l * 256 * 128,
                                    b1 + (size_t)l * 256, psum, psq, NN);
    k_finred<<<256, 256, 0, stream>>>(psum, psq, NB, 256, g1 + (size_t)l * 256,
                                      be1 + (size_t)l * 256, tsc1, tsh1, 1.0f / NN);
    k_fused<<<NB, 512, 0, stream>>>(h0, W1t + (size_t)l * 256 * 128,
                                    b1 + (size_t)l * 256, tsc1, tsh1,
                                    W2t + (size_t)l * 128 * 256,
                                    b2 + (size_t)l * 128, xp, psum, psq, NN);
    k_finred<<<128, 256, 0, stream>>>(psum, psq, NB, 128, gbn + (size_t)l * 128,
                                      bbn + (size_t)l * 128, tscX, tshX, 1.0f / NN);
  }

  k_pool<<<GG, 512, 0, stream>>>(xp, batch, tscX, tshX, zbuf, NN);
  k_cls1<<<GG, 128, 0, stream>>>(zbuf, cW1, cb1, z1);
  k_statz<<<128, 256, 0, stream>>>(z1, cg, cbeta, tscX, tshX);
  k_cls2<<<GG, 128, 0, stream>>>(z1, tscX, tshX, cW2, cb2, cW3, cb3, out);
}